// Round 15
// baseline (176.161 us; speedup 1.0000x reference)
//
#include <hip/hip_runtime.h>
#include <hip/hip_bf16.h>
#include <math.h>

#define CB   128   // input channels
#define CMID 64    // compressed channels
#define NENC 100   // encoder out channels (25 * 2 * 2)
#define HH   48
#define WW   48
#define BB   4
#define HW   (HH*WW)          // 2304
#define H2   (HH*2)           // 96
#define W2   (WW*2)           // 96
#define PS   56                // padded row stride: 224B -> rows 16B-aligned
#define PROWS 50               // 48 interior rows + 1 halo row each side
#define PCOL0 4                // interior starts at col 4
#define PLANE (PROWS*PS)       // 2800 floats per (b,cm) plane
#define EG   2                 // e-outputs per conv3 block (data reuse)
#define NHALO4 (BB*CMID*124)   // 31744 halo float4s

// ---------------- Kernel 1: fused gamma-reduce + pow + halo-zero ----------------
__global__ __launch_bounds__(256) void pow_kernel(const float* __restrict__ x,
                                                  float* __restrict__ xg,
                                                  float* __restrict__ y1p) {
    int tid = threadIdx.x;
    int bid = blockIdx.x;
    int b = bid / (CB * HW / 4 / 256);        // 288 blocks per batch

    const float* xb = x + (size_t)b * CB * HW;
    const float4* R4 = (const float4*)xb;
    const float4* G4 = (const float4*)(xb + HW);
    const float4* B4 = (const float4*)(xb + 2 * HW);
    float s = 0.f, s2 = 0.f;
    for (int i = tid; i < HW / 4; i += 256) {
        float4 r = R4[i], g = G4[i], bl = B4[i];
        float g0 = 0.299f * r.x + 0.587f * g.x + 0.114f * bl.x;
        float g1 = 0.299f * r.y + 0.587f * g.y + 0.114f * bl.y;
        float g2 = 0.299f * r.z + 0.587f * g.z + 0.114f * bl.z;
        float g3 = 0.299f * r.w + 0.587f * g.w + 0.114f * bl.w;
        s  += (g0 + g1) + (g2 + g3);
        s2 += (g0 * g0 + g1 * g1) + (g2 * g2 + g3 * g3);
    }
    for (int o = 32; o > 0; o >>= 1) {
        s  += __shfl_down(s, o);
        s2 += __shfl_down(s2, o);
    }
    __shared__ float ss[4], ss2[4], gsh;
    int wid = tid >> 6;
    if ((tid & 63) == 0) { ss[wid] = s; ss2[wid] = s2; }
    __syncthreads();
    if (tid == 0) {
        float S = ss[0] + ss[1] + ss[2] + ss[3];
        float S2 = ss2[0] + ss2[1] + ss2[2] + ss2[3];
        const float N = (float)HW;
        float gm = S / N;
        float var = (S2 - S * S / N) / (N - 1.0f);
        var = fmaxf(var, 0.f);
        float gs = sqrtf(var);
        float gam = 0.8f + 0.4f * gm / (gm + fmaxf(gs, 1e-6f));
        gsh = fminf(fmaxf(gam, 0.8f), 1.2f);
    }
    __syncthreads();
    float gam = gsh;

    int idx = bid * 256 + tid;
    float4 xv = ((const float4*)x)[idx];
    float4 r;
    r.x = __expf(gam * __logf(xv.x + 1e-6f));
    r.y = __expf(gam * __logf(xv.y + 1e-6f));
    r.z = __expf(gam * __logf(xv.z + 1e-6f));
    r.w = __expf(gam * __logf(xv.w + 1e-6f));
    ((float4*)xg)[idx] = r;

    if (idx < NHALO4) {
        int plane = idx / 124;
        int t = idx % 124;
        float* p = y1p + (size_t)plane * PLANE;
        float4 z = make_float4(0.f, 0.f, 0.f, 0.f);
        if (t < 14) {
            *(float4*)(p + t * 4) = z;
        } else if (t < 28) {
            *(float4*)(p + 49 * PS + (t - 14) * 4) = z;
        } else {
            int sIdx = t - 28;
            int rr = 1 + (sIdx >> 1);
            int col = (sIdx & 1) ? 52 : 0;
            *(float4*)(p + rr * PS + col) = z;
        }
    }
}

// ---------------- Kernel 2: conv1x1 + BN + SiLU — depth-8 manual pipeline ----------
__global__ __launch_bounds__(256) void conv1_kernel(
        const float* __restrict__ xg, const float* __restrict__ w,
        const float* __restrict__ g, const float* __restrict__ bta,
        const float* __restrict__ m, const float* __restrict__ vv,
        float* __restrict__ y1p) {
    int idx = blockIdx.x * 256 + threadIdx.x;
    const int PG = HW / 4;                 // 576 pixel-groups
    int pg = idx % PG;
    int cm = (idx / PG) % CMID;
    int b  = idx / (CMID * PG);
    const float4* xb = (const float4*)(xg + (size_t)b * CB * HW) + pg;
    const float* wc = w + cm * CB;         // wave-uniform (pg fastest) -> scalar loads
    float4 acc = {0.f, 0.f, 0.f, 0.f};

    float4 xr[8]; float wr[8];
#pragma unroll
    for (int j = 0; j < 8; j++) { xr[j] = xb[(size_t)j * PG]; wr[j] = wc[j]; }

    for (int c = 0; c < CB - 8; c += 8) {
        float4 nx[8]; float nw[8];
#pragma unroll
        for (int j = 0; j < 8; j++) {
            nx[j] = xb[(size_t)(c + 8 + j) * PG];
            nw[j] = wc[c + 8 + j];
        }
#pragma unroll
        for (int j = 0; j < 8; j++) {
            acc.x = fmaf(wr[j], xr[j].x, acc.x);
            acc.y = fmaf(wr[j], xr[j].y, acc.y);
            acc.z = fmaf(wr[j], xr[j].z, acc.z);
            acc.w = fmaf(wr[j], xr[j].w, acc.w);
        }
#pragma unroll
        for (int j = 0; j < 8; j++) { xr[j] = nx[j]; wr[j] = nw[j]; }
    }
#pragma unroll
    for (int j = 0; j < 8; j++) {
        acc.x = fmaf(wr[j], xr[j].x, acc.x);
        acc.y = fmaf(wr[j], xr[j].y, acc.y);
        acc.z = fmaf(wr[j], xr[j].z, acc.z);
        acc.w = fmaf(wr[j], xr[j].w, acc.w);
    }

    float sc = g[cm] * rsqrtf(vv[cm] + 1e-3f);
    float sh = bta[cm] - m[cm] * sc;
    float4 o;
    float t;
    t = acc.x * sc + sh; o.x = t / (1.f + __expf(-t));
    t = acc.y * sc + sh; o.y = t / (1.f + __expf(-t));
    t = acc.z * sc + sh; o.z = t / (1.f + __expf(-t));
    t = acc.w * sc + sh; o.w = t / (1.f + __expf(-t));
    int row = pg / 12, col = (pg % 12) * 4;
    float* dst = y1p + ((size_t)(b * CMID + cm)) * PLANE + (row + 1) * PS + (col + PCOL0);
    *(float4*)dst = o;   // 16B-aligned
}

// ---------------- Kernel 3: conv3x3 + BN — e-blocked (EG=2) + dist-1 pipeline ----
#define FMA4(A0,A1,A2,A3, wa,wb,wc, lf,mm,rt) \
    A0 = fmaf(wa, lf,   fmaf(wb, mm.x, fmaf(wc, mm.y, A0))); \
    A1 = fmaf(wa, mm.x, fmaf(wb, mm.y, fmaf(wc, mm.z, A1))); \
    A2 = fmaf(wa, mm.y, fmaf(wb, mm.z, fmaf(wc, mm.w, A2))); \
    A3 = fmaf(wa, mm.z, fmaf(wb, mm.w, fmaf(wc, rt,   A3)));

__global__ __launch_bounds__(192) void conv3_kernel(
        const float* __restrict__ y1p, const float* __restrict__ w,
        const float* __restrict__ g, const float* __restrict__ bta,
        const float* __restrict__ m, const float* __restrict__ vv,
        float* __restrict__ wk2n) {
    int blk = blockIdx.x;
    int eg  = blk % (NENC / EG);
    int tmp = blk / (NENC / EG);
    int rb  = tmp % 3, b = tmp / 3;
    int e0  = eg * EG;
    int t   = threadIdx.x;
    int row = rb * 16 + t / 12;
    int c0  = (t % 12) * 4;
    const float* wb0 = w + (size_t)e0 * CMID * 9;
    const float* wb1 = wb0 + CMID * 9;
    const float* yb = y1p + (size_t)b * CMID * PLANE + row * PS + (c0 + PCOL0);

    float a00 = 0.f, a01 = 0.f, a02 = 0.f, a03 = 0.f;
    float a10 = 0.f, a11 = 0.f, a12 = 0.f, a13 = 0.f;

    float  lf0 = yb[-1];        float4 m0 = *(const float4*)yb;          float rt0 = yb[4];
    float  lf1 = yb[PS-1];      float4 m1 = *(const float4*)(yb+PS);     float rt1 = yb[PS+4];
    float  lf2 = yb[2*PS-1];    float4 m2 = *(const float4*)(yb+2*PS);   float rt2 = yb[2*PS+4];
    float u00 = wb0[0], u01 = wb0[1], u02 = wb0[2];
    float u10 = wb0[3], u11 = wb0[4], u12 = wb0[5];
    float u20 = wb0[6], u21 = wb0[7], u22 = wb0[8];
    float v00 = wb1[0], v01 = wb1[1], v02 = wb1[2];
    float v10 = wb1[3], v11 = wb1[4], v12 = wb1[5];
    float v20 = wb1[6], v21 = wb1[7], v22 = wb1[8];

    for (int cm = 0; cm < CMID - 1; ++cm) {
        const float* yn = yb + (size_t)(cm + 1) * PLANE;
        float  nlf0 = yn[-1];       float4 nm0 = *(const float4*)yn;         float nrt0 = yn[4];
        float  nlf1 = yn[PS-1];     float4 nm1 = *(const float4*)(yn+PS);    float nrt1 = yn[PS+4];
        float  nlf2 = yn[2*PS-1];   float4 nm2 = *(const float4*)(yn+2*PS);  float nrt2 = yn[2*PS+4];
        const float* wn0 = wb0 + (cm + 1) * 9;
        const float* wn1 = wb1 + (cm + 1) * 9;
        float nu00 = wn0[0], nu01 = wn0[1], nu02 = wn0[2];
        float nu10 = wn0[3], nu11 = wn0[4], nu12 = wn0[5];
        float nu20 = wn0[6], nu21 = wn0[7], nu22 = wn0[8];
        float nv00 = wn1[0], nv01 = wn1[1], nv02 = wn1[2];
        float nv10 = wn1[3], nv11 = wn1[4], nv12 = wn1[5];
        float nv20 = wn1[6], nv21 = wn1[7], nv22 = wn1[8];

        FMA4(a00,a01,a02,a03, u00,u01,u02, lf0,m0,rt0)
        FMA4(a00,a01,a02,a03, u10,u11,u12, lf1,m1,rt1)
        FMA4(a00,a01,a02,a03, u20,u21,u22, lf2,m2,rt2)
        FMA4(a10,a11,a12,a13, v00,v01,v02, lf0,m0,rt0)
        FMA4(a10,a11,a12,a13, v10,v11,v12, lf1,m1,rt1)
        FMA4(a10,a11,a12,a13, v20,v21,v22, lf2,m2,rt2)

        lf0 = nlf0; m0 = nm0; rt0 = nrt0;
        lf1 = nlf1; m1 = nm1; rt1 = nrt1;
        lf2 = nlf2; m2 = nm2; rt2 = nrt2;
        u00 = nu00; u01 = nu01; u02 = nu02;
        u10 = nu10; u11 = nu11; u12 = nu12;
        u20 = nu20; u21 = nu21; u22 = nu22;
        v00 = nv00; v01 = nv01; v02 = nv02;
        v10 = nv10; v11 = nv11; v12 = nv12;
        v20 = nv20; v21 = nv21; v22 = nv22;
    }
    FMA4(a00,a01,a02,a03, u00,u01,u02, lf0,m0,rt0)
    FMA4(a00,a01,a02,a03, u10,u11,u12, lf1,m1,rt1)
    FMA4(a00,a01,a02,a03, u20,u21,u22, lf2,m2,rt2)
    FMA4(a10,a11,a12,a13, v00,v01,v02, lf0,m0,rt0)
    FMA4(a10,a11,a12,a13, v10,v11,v12, lf1,m1,rt1)
    FMA4(a10,a11,a12,a13, v20,v21,v22, lf2,m2,rt2)

    float sc0 = g[e0] * rsqrtf(vv[e0] + 1e-3f);
    float sh0 = bta[e0] - m[e0] * sc0;
    float sc1 = g[e0+1] * rsqrtf(vv[e0+1] + 1e-3f);
    float sh1 = bta[e0+1] - m[e0+1] * sc1;
    int kk = e0 >> 2, off0 = e0 & 3;
    float* op = wk2n + (((size_t)(b * 25 + kk) * HW + row * WW + c0) << 2) + off0;
    *(float2*)(op + 0)  = make_float2(a00*sc0+sh0, a10*sc1+sh1);
    *(float2*)(op + 4)  = make_float2(a01*sc0+sh0, a11*sc1+sh1);
    *(float2*)(op + 8)  = make_float2(a02*sc0+sh0, a12*sc1+sh1);
    *(float2*)(op + 12) = make_float2(a03*sc0+sh0, a13*sc1+sh1);
}

// ---------------- Kernel 4: fused softmax + gather — 1152 blocks ----------------
// block = (b, h, wseg of 8 source cols); thread = (c in 128, si in 2).
// Each thread: 16 output cols of row 2h+si from 4 aligned window float4s.
__global__ __launch_bounds__(256) void sg_kernel(const float* __restrict__ xg,
                                                 const float* __restrict__ wk2n,
                                                 float* __restrict__ out) {
    int blk = blockIdx.x;                  // (b*48 + h)*6 + wseg
    int wseg = blk % 6;
    int bh = blk / 6;
    int h = bh % HH, b = bh / HH;
    int tid = threadIdx.x;
    int c0 = wseg * 8;

    __shared__ float raw[25 * 8 * 4];      // [k][wl][off]  (3.2 KB)
    __shared__ float wsm[25 * 2 * 16];     // [k][si][t]    (3.2 KB)

    // phase 1a: load 25 x 8 float4 score slice
    if (tid < 200) {
        int k = tid / 8, wl = tid % 8;
        ((float4*)raw)[tid] =
            ((const float4*)wk2n)[((size_t)(b * 25 + k)) * HW + h * WW + c0 + wl];
    }
    __syncthreads();
    // phase 1b: 32 softmaxes
    if (tid < 32) {
        int wl = tid >> 2, off = tid & 3;
        float v[25]; float mx = -1e30f;
#pragma unroll
        for (int k = 0; k < 25; k++) { v[k] = raw[(k * 8 + wl) * 4 + off]; mx = fmaxf(mx, v[k]); }
        float sum = 0.f;
#pragma unroll
        for (int k = 0; k < 25; k++) { v[k] = __expf(v[k] - mx); sum += v[k]; }
        float inv = 1.f / sum;
        int si = off >> 1, sj = off & 1;
#pragma unroll
        for (int k = 0; k < 25; k++) wsm[k * 32 + si * 16 + 2 * wl + sj] = v[k] * inv;
    }
    __syncthreads();

    // phase 2: thread (c, si) -> 16 output cols of row 2h+si
    int c = tid >> 1, si = tid & 1;
    const float* xb = xg + ((size_t)b * CB + c) * HW;
    const float4* wsm4 = (const float4*)wsm;
    const float4 Z4 = make_float4(0.f, 0.f, 0.f, 0.f);
    float acc[16];
#pragma unroll
    for (int t = 0; t < 16; t++) acc[t] = 0.f;

#pragma unroll
    for (int i = 0; i < 5; i++) {
        int hr = h + i - 2;
        bool rv = (hr >= 0) && (hr < HH);
        const float* rp = xb + hr * WW + c0;
        float4 A  = (rv && wseg > 0) ? *(const float4*)(rp - 4) : Z4;
        float4 Bq = rv               ? *(const float4*)(rp)     : Z4;
        float4 Cq = rv               ? *(const float4*)(rp + 4) : Z4;
        float4 D  = (rv && wseg < 5) ? *(const float4*)(rp + 8) : Z4;
        float v[16] = {A.x, A.y, A.z, A.w, Bq.x, Bq.y, Bq.z, Bq.w,
                       Cq.x, Cq.y, Cq.z, Cq.w, D.x, D.y, D.z, D.w};
#pragma unroll
        for (int j = 0; j < 5; j++) {
            int k = i * 5 + j;
            float4 wA = wsm4[k * 8 + si * 4 + 0];
            float4 wB = wsm4[k * 8 + si * 4 + 1];
            float4 wC = wsm4[k * 8 + si * 4 + 2];
            float4 wD = wsm4[k * 8 + si * 4 + 3];
            acc[0]  = fmaf(wA.x, v[j + 2], acc[0]);
            acc[1]  = fmaf(wA.y, v[j + 2], acc[1]);
            acc[2]  = fmaf(wA.z, v[j + 3], acc[2]);
            acc[3]  = fmaf(wA.w, v[j + 3], acc[3]);
            acc[4]  = fmaf(wB.x, v[j + 4], acc[4]);
            acc[5]  = fmaf(wB.y, v[j + 4], acc[5]);
            acc[6]  = fmaf(wB.z, v[j + 5], acc[6]);
            acc[7]  = fmaf(wB.w, v[j + 5], acc[7]);
            acc[8]  = fmaf(wC.x, v[j + 6], acc[8]);
            acc[9]  = fmaf(wC.y, v[j + 6], acc[9]);
            acc[10] = fmaf(wC.z, v[j + 7], acc[10]);
            acc[11] = fmaf(wC.w, v[j + 7], acc[11]);
            acc[12] = fmaf(wD.x, v[j + 8], acc[12]);
            acc[13] = fmaf(wD.y, v[j + 8], acc[13]);
            acc[14] = fmaf(wD.z, v[j + 9], acc[14]);
            acc[15] = fmaf(wD.w, v[j + 9], acc[15]);
        }
    }

    float* ob = out + (((size_t)b * CB + c) * H2 + 2 * h + si) * W2 + 16 * wseg;
    *(float4*)(ob + 0)  = make_float4(acc[0],  acc[1],  acc[2],  acc[3]);
    *(float4*)(ob + 4)  = make_float4(acc[4],  acc[5],  acc[6],  acc[7]);
    *(float4*)(ob + 8)  = make_float4(acc[8],  acc[9],  acc[10], acc[11]);
    *(float4*)(ob + 12) = make_float4(acc[12], acc[13], acc[14], acc[15]);
}

extern "C" void kernel_launch(void* const* d_in, const int* in_sizes, int n_in,
                              void* d_out, int out_size, void* d_ws, size_t ws_size,
                              hipStream_t stream) {
    const float* x       = (const float*)d_in[0];
    const float* comp_w  = (const float*)d_in[1];
    const float* comp_g  = (const float*)d_in[2];
    const float* comp_b  = (const float*)d_in[3];
    const float* comp_m  = (const float*)d_in[4];
    const float* comp_v  = (const float*)d_in[5];
    const float* enc_w   = (const float*)d_in[6];
    const float* enc_g   = (const float*)d_in[7];
    const float* enc_b   = (const float*)d_in[8];
    const float* enc_m   = (const float*)d_in[9];
    const float* enc_v   = (const float*)d_in[10];
    float* out = (float*)d_out;

    float* ws = (float*)d_ws;
    float* xg    = ws;                                   // 1,179,648
    float* wk2n  = xg + (size_t)BB * CB * HW;            // 921,600  [b][25][HW][4]
    float* y1p   = wk2n + (size_t)BB * 25 * HW * 4;      // 716,800
    // total floats: 2,818,048 (~11.3 MB)

    {   // fused gamma + pow + halo-zero
        int total4 = BB * CB * HW / 4;                   // 1152 blocks
        pow_kernel<<<total4 / 256, 256, 0, stream>>>(x, xg, y1p);
    }
    {
        int total = BB * CMID * (HW / 4);                // 576 blocks
        conv1_kernel<<<total / 256, 256, 0, stream>>>(
            xg, comp_w, comp_g, comp_b, comp_m, comp_v, y1p);
    }
    conv3_kernel<<<BB * 3 * (NENC / EG), 192, 0, stream>>>(
        y1p, enc_w, enc_g, enc_b, enc_m, enc_v, wk2n);
    sg_kernel<<<BB * HH * 6, 256, 0, stream>>>(xg, wk2n, out);
}